// Round 1
// baseline (52137.408 us; speedup 1.0000x reference)
//
#include <hip/hip_runtime.h>
#include <stdint.h>
#include <stddef.h>

// Problem constants
#define Bn 32
#define Tn 1024
#define In 512
#define Hn 1024
#define NBLK 256   // persistent blocks, one N-tile (16 gate rows = 4 h-cols) each
#define NTHR 256   // 4 waves; K split 4-ways across waves

typedef _Float16 half8 __attribute__((ext_vector_type(8)));
typedef float float4x __attribute__((ext_vector_type(4)));

// ---------------------------------------------------------------------------
// Workspace layout (bytes):
//   Wp   : 256 nb * 48 kc * 64 lane * 8 = 6,291,456 halves  (12.58 MB)
//   bias : 4096 floats packed as bias[nb*16 + rsel]          (16 KB)
//   xp   : 1024 t * 2 mt * 16 kc * 64 * 8 = 16,777,216 halves (33.55 MB)
//   hp   : 2 buf * 2 mt * 32 kc * 64 * 8 = 65,536 halves      (128 KB)
//   bar  : barrier counter                                    (256 B)
// total ~46.3 MB
// ---------------------------------------------------------------------------

// Pack W = [W_ih | W_hh] rows into MFMA B-fragment-linear layout, fp16.
// Block nb owns h-cols [nb*4, nb*4+4); rowsel r in [0,16): gate g=r>>2,
// col c = nb*4 + (r&3); W row = g*1024 + c.
__global__ void prep_w_k(const float* __restrict__ Wih, const float* __restrict__ Whh,
                         const float* __restrict__ bih, const float* __restrict__ bhh,
                         _Float16* __restrict__ Wp, float* __restrict__ bias) {
  int nb = blockIdx.x;
  for (int p = threadIdx.x; p < 48 * 64; p += NTHR) {
    int kc = p >> 6, lane = p & 63;
    int r = lane & 15;
    int row = ((r >> 2) << 10) + (nb << 2) + (r & 3);
    int kb = (kc << 5) + ((lane >> 4) << 3);
    half8 v;
#pragma unroll
    for (int j = 0; j < 8; ++j) {
      int k = kb + j;
      float w = (k < In) ? Wih[(size_t)row * In + k] : Whh[(size_t)row * Hn + (k - In)];
      v[j] = (_Float16)w;
    }
    *(half8*)(Wp + (((size_t)nb * 48 + kc) * 64 + lane) * 8) = v;
  }
  if (threadIdx.x < 16) {
    int r = threadIdx.x;
    int row = ((r >> 2) << 10) + (nb << 2) + (r & 3);
    bias[nb * 16 + r] = bih[row] + bhh[row];
  }
}

// Convert inputs [B,T,I] fp32 -> A-fragment-linear fp16 per timestep.
// A row m = batch = (lane&15) + 16*mt ; k = kc*32 + (lane>>4)*8 + j.
__global__ void prep_x_k(const float* __restrict__ x, _Float16* __restrict__ xp) {
  int t = blockIdx.x;
  for (int p = threadIdx.x; p < 2048; p += NTHR) {
    int mt = p >> 10, rem = p & 1023, kc = rem >> 6, lane = rem & 63;
    int b = (lane & 15) + (mt << 4);
    int k = (kc << 5) + ((lane >> 4) << 3);
    const float* src = x + ((size_t)b * Tn + t) * In + k;
    half8 v;
#pragma unroll
    for (int j = 0; j < 8; ++j) v[j] = (_Float16)src[j];
    *(half8*)(xp + (((size_t)(t * 2 + mt) * 16 + kc) * 64 + lane) * 8) = v;
  }
}

// Persistent LSTM kernel: 256 blocks, grid barrier per timestep.
__global__ __launch_bounds__(NTHR) void lstm_k(
    const _Float16* __restrict__ xp, const _Float16* __restrict__ Wp,
    const float* __restrict__ bias, _Float16* __restrict__ hp,
    int* __restrict__ bar, float* __restrict__ out) {
  __shared__ float red[4 * 2 * 4 * 64];  // [wave][mt][reg][lane] partials, 8KB
  __shared__ float gbuf[512];            // reduced gates [b][rsel], 2KB

  const int tid = threadIdx.x;
  const int wave = tid >> 6, lane = tid & 63;
  const int nb = blockIdx.x;

  // pointwise identity (threads 0..127): (batch pb, local col pc)
  const int pb = tid >> 2, pc = tid & 3;
  const int col = (nb << 2) + pc;
  float creg = 0.f;  // cell state lives in a register for the whole sequence

  const float* biasp = bias + nb * 16;

  for (int t = 0; t < Tn; ++t) {
    float4x acc0 = {0.f, 0.f, 0.f, 0.f};
    float4x acc1 = {0.f, 0.f, 0.f, 0.f};

    // ---- x part: this wave covers kc in [wave*4, wave*4+4), K 0..511 ----
    const _Float16* xbase = xp + (size_t)t * 2 * 16 * 64 * 8;
    const _Float16* wbase = Wp + (size_t)nb * 48 * 64 * 8;
#pragma unroll
    for (int kk = 0; kk < 4; ++kk) {
      int kc = wave * 4 + kk;
      half8 a0 = *(const half8*)(xbase + ((size_t)(0 * 16 + kc) * 64 + lane) * 8);
      half8 a1 = *(const half8*)(xbase + ((size_t)(1 * 16 + kc) * 64 + lane) * 8);
      half8 wf = *(const half8*)(wbase + ((size_t)kc * 64 + lane) * 8);
      acc0 = __builtin_amdgcn_mfma_f32_16x16x32_f16(a0, wf, acc0, 0, 0, 0);
      acc1 = __builtin_amdgcn_mfma_f32_16x16x32_f16(a1, wf, acc1, 0, 0, 0);
    }

    // ---- h part: this wave covers kc2 in [wave*8, wave*8+8), K 512..1535 ----
    const int cur = t & 1;
    const _Float16* hbase = hp + (size_t)cur * 2 * 32 * 64 * 8;
#pragma unroll
    for (int kk = 0; kk < 8; ++kk) {
      int kc2 = wave * 8 + kk;
      half8 a0 = *(const half8*)(hbase + ((size_t)(0 * 32 + kc2) * 64 + lane) * 8);
      half8 a1 = *(const half8*)(hbase + ((size_t)(1 * 32 + kc2) * 64 + lane) * 8);
      half8 wf = *(const half8*)(wbase + ((size_t)(16 + kc2) * 64 + lane) * 8);
      acc0 = __builtin_amdgcn_mfma_f32_16x16x32_f16(a0, wf, acc0, 0, 0, 0);
      acc1 = __builtin_amdgcn_mfma_f32_16x16x32_f16(a1, wf, acc1, 0, 0, 0);
    }

    // ---- cross-wave K reduction through LDS ----
#pragma unroll
    for (int r = 0; r < 4; ++r) {
      red[((wave * 2 + 0) * 4 + r) * 64 + lane] = acc0[r];
      red[((wave * 2 + 1) * 4 + r) * 64 + lane] = acc1[r];
    }
    __syncthreads();

    // reduce: gate value (b, rsel); D layout: col=lane&15=rsel, row=quad*4+reg=b%16
    for (int p = tid; p < 512; p += NTHR) {
      int b = p >> 4, rs = p & 15;
      int mt = b >> 4, quad = (b >> 2) & 3, reg = b & 3;
      int l2 = quad * 16 + rs;
      float s = biasp[rs];
#pragma unroll
      for (int w = 0; w < 4; ++w) s += red[((w * 2 + mt) * 4 + reg) * 64 + l2];
      gbuf[p] = s;
    }
    __syncthreads();

    // ---- pointwise LSTM cell (threads 0..127) ----
    if (tid < 128) {
      float gi = gbuf[pb * 16 + 0 + pc];
      float gf = gbuf[pb * 16 + 4 + pc];
      float gg = gbuf[pb * 16 + 8 + pc];
      float go = gbuf[pb * 16 + 12 + pc];
      float ig = 1.f / (1.f + __expf(-gi));
      float fg = 1.f / (1.f + __expf(-gf));
      float g2 = 1.f - 2.f / (1.f + __expf(2.f * gg));  // tanh
      float og = 1.f / (1.f + __expf(-go));
      creg = fg * creg + ig * g2;
      float hv = og * (1.f - 2.f / (1.f + __expf(2.f * creg)));

      out[((size_t)pb * Tn + t) * Hn + col] = hv;

      // write h into next buffer, consumer-fragment order
      int nxt = cur ^ 1;
      int mt = pb >> 4;
      int kc2 = col >> 5;
      int l2 = (pb & 15) + (((col >> 3) & 3) << 4);
      int j = col & 7;
      hp[(((size_t)(nxt * 2 + mt) * 32 + kc2) * 64 + l2) * 8 + j] = (_Float16)hv;

      if (t == Tn - 1) {
        out[(size_t)Bn * Tn * Hn + (size_t)pb * Hn + col] = hv;                       // h_T
        out[(size_t)Bn * Tn * Hn + (size_t)Bn * Hn + (size_t)pb * Hn + col] = creg;  // c_T
      }
    }

    // ---- grid barrier: release writes, arrive, spin, acquire ----
    __threadfence();   // release: h writes visible agent-scope
    __syncthreads();
    if (tid == 0) {
      __hip_atomic_fetch_add(bar, 1, __ATOMIC_RELEASE, __HIP_MEMORY_SCOPE_AGENT);
      int target = (t + 1) * NBLK;
      while (__hip_atomic_load(bar, __ATOMIC_ACQUIRE, __HIP_MEMORY_SCOPE_AGENT) < target)
        __builtin_amdgcn_s_sleep(2);
    }
    __syncthreads();
    __threadfence();   // acquire: invalidate caches before reading new h
  }
}

extern "C" void kernel_launch(void* const* d_in, const int* in_sizes, int n_in,
                              void* d_out, int out_size, void* d_ws, size_t ws_size,
                              hipStream_t stream) {
  const float* x   = (const float*)d_in[0];
  const float* Wih = (const float*)d_in[1];
  const float* Whh = (const float*)d_in[2];
  const float* bih = (const float*)d_in[3];
  const float* bhh = (const float*)d_in[4];
  float* out = (float*)d_out;

  char* ws = (char*)d_ws;
  _Float16* Wp  = (_Float16*)ws;                                  // 6,291,456 halves
  float*    bias = (float*)(ws + (size_t)6291456 * 2);            // 4096 floats
  _Float16* xp  = (_Float16*)(ws + (size_t)6291456 * 2 + 16384);  // 16,777,216 halves
  _Float16* hp  = xp + (size_t)16777216;                          // 65,536 halves
  int*      bar = (int*)(hp + 65536);

  prep_w_k<<<NBLK, NTHR, 0, stream>>>(Wih, Whh, bih, bhh, Wp, bias);
  prep_x_k<<<Tn, NTHR, 0, stream>>>(x, xp);
  hipMemsetAsync(hp, 0, 32768 * sizeof(_Float16), stream);  // zero h buffer 0
  hipMemsetAsync(bar, 0, 256, stream);                       // zero barrier
  lstm_k<<<NBLK, NTHR, 0, stream>>>(xp, Wp, bias, hp, bar, out);
}

// Round 2
// 29963.107 us; speedup vs baseline: 1.7401x; 1.7401x over previous
//
#include <hip/hip_runtime.h>
#include <stdint.h>
#include <stddef.h>

// Problem constants
#define Bn 32
#define Tn 1024
#define In 512
#define Hn 1024
#define NBLK 256   // persistent blocks, one N-tile (16 gate rows = 4 h-cols) each
#define NTHR 256   // 4 waves; K split 4-ways across waves

typedef _Float16 half8 __attribute__((ext_vector_type(8)));
typedef float float4x __attribute__((ext_vector_type(4)));

// ---------------------------------------------------------------------------
// Workspace layout (bytes):
//   Wp    : 256 nb * 48 kc * 64 lane * 8 = 6,291,456 halves  (12.58 MB)
//   bias  : 4096 floats packed as bias[nb*16 + rsel]          (16 KB)
//   xp    : 1024 t * 2 mt * 16 kc * 64 * 8 = 16,777,216 halves (33.55 MB)
//   hp    : 2 buf * 2 mt * 32 kc * 64 * 8 = 65,536 halves      (128 KB)
//   flags : 256 ints (one per block — contention-free barrier)  (1 KB)
// ---------------------------------------------------------------------------

// Pack W = [W_ih | W_hh] rows into MFMA B-fragment-linear layout, fp16.
__global__ void prep_w_k(const float* __restrict__ Wih, const float* __restrict__ Whh,
                         const float* __restrict__ bih, const float* __restrict__ bhh,
                         _Float16* __restrict__ Wp, float* __restrict__ bias) {
  int nb = blockIdx.x;
  for (int p = threadIdx.x; p < 48 * 64; p += NTHR) {
    int kc = p >> 6, lane = p & 63;
    int r = lane & 15;
    int row = ((r >> 2) << 10) + (nb << 2) + (r & 3);
    int kb = (kc << 5) + ((lane >> 4) << 3);
    half8 v;
#pragma unroll
    for (int j = 0; j < 8; ++j) {
      int k = kb + j;
      float w = (k < In) ? Wih[(size_t)row * In + k] : Whh[(size_t)row * Hn + (k - In)];
      v[j] = (_Float16)w;
    }
    *(half8*)(Wp + (((size_t)nb * 48 + kc) * 64 + lane) * 8) = v;
  }
  if (threadIdx.x < 16) {
    int r = threadIdx.x;
    int row = ((r >> 2) << 10) + (nb << 2) + (r & 3);
    bias[nb * 16 + r] = bih[row] + bhh[row];
  }
}

// Convert inputs [B,T,I] fp32 -> A-fragment-linear fp16 per timestep.
__global__ void prep_x_k(const float* __restrict__ x, _Float16* __restrict__ xp) {
  int t = blockIdx.x;
  for (int p = threadIdx.x; p < 2048; p += NTHR) {
    int mt = p >> 10, rem = p & 1023, kc = rem >> 6, lane = rem & 63;
    int b = (lane & 15) + (mt << 4);
    int k = (kc << 5) + ((lane >> 4) << 3);
    const float* src = x + ((size_t)b * Tn + t) * In + k;
    half8 v;
#pragma unroll
    for (int j = 0; j < 8; ++j) v[j] = (_Float16)src[j];
    *(half8*)(xp + (((size_t)(t * 2 + mt) * 16 + kc) * 64 + lane) * 8) = v;
  }
}

#define MFMA(a, b, c) __builtin_amdgcn_mfma_f32_16x16x32_f16((a), (b), (c), 0, 0, 0)

// Persistent LSTM kernel: 256 blocks, flag-array grid barrier per timestep.
__global__ __launch_bounds__(NTHR, 1) void lstm_k(
    const _Float16* __restrict__ xp, const _Float16* __restrict__ Wp,
    const float* __restrict__ bias, _Float16* __restrict__ hp,
    int* __restrict__ flags, float* __restrict__ out) {
  __shared__ float red[4 * 2 * 4 * 64];  // [wave][mt][reg][lane] partials, 8KB
  __shared__ float gbuf[512];            // reduced gates [b][rsel], 2KB

  const int tid = threadIdx.x;
  const int wave = tid >> 6, lane = tid & 63;
  const int nb = blockIdx.x;

  // pointwise identity (threads 0..127): (batch pb, local col pc)
  const int pb = tid >> 2, pc = tid & 3;
  const int col = (nb << 2) + pc;
  float creg = 0.f;  // cell state lives in a register for the whole sequence

  const float* biasp = bias + nb * 16;

  // ---- W resident in VGPRs for the whole sequence (immune to L2 inval) ----
  const _Float16* wbase = Wp + (size_t)nb * 48 * 64 * 8;
  half8 wx[4], wh[8];
#pragma unroll
  for (int i = 0; i < 4; ++i)
    wx[i] = *(const half8*)(wbase + ((size_t)(wave * 4 + i) * 64 + lane) * 8);
#pragma unroll
  for (int i = 0; i < 8; ++i)
    wh[i] = *(const half8*)(wbase + ((size_t)(16 + wave * 8 + i) * 64 + lane) * 8);

  // ---- preload x fragments for t=0 ----
  half8 xa[2][4], xb[2][4];
#pragma unroll
  for (int mt = 0; mt < 2; ++mt)
#pragma unroll
    for (int kk = 0; kk < 4; ++kk)
      xa[mt][kk] = *(const half8*)(xp + ((size_t)(mt * 16 + wave * 4 + kk) * 64 + lane) * 8);

  for (int t = 0; t < Tn; ++t) {
    const int cur = t & 1;
    const _Float16* hbase = hp + (size_t)cur * 2 * 32 * 64 * 8;

    // issue all h loads first (longest-latency: cross-XCD via L3)
    half8 ha[2][8];
#pragma unroll
    for (int mt = 0; mt < 2; ++mt)
#pragma unroll
      for (int kk = 0; kk < 8; ++kk)
        ha[mt][kk] = *(const half8*)(hbase + ((size_t)(mt * 32 + wave * 8 + kk) * 64 + lane) * 8);

    float4x acc0 = {0.f, 0.f, 0.f, 0.f};
    float4x acc1 = {0.f, 0.f, 0.f, 0.f};

    // x part (W in regs, x in regs — no memory waits)
#pragma unroll
    for (int kk = 0; kk < 4; ++kk) {
      acc0 = MFMA(xa[0][kk], wx[kk], acc0);
      acc1 = MFMA(xa[1][kk], wx[kk], acc1);
    }
    // h part
#pragma unroll
    for (int kk = 0; kk < 8; ++kk) {
      acc0 = MFMA(ha[0][kk], wh[kk], acc0);
      acc1 = MFMA(ha[1][kk], wh[kk], acc1);
    }

    // ---- cross-wave K reduction through LDS ----
#pragma unroll
    for (int r = 0; r < 4; ++r) {
      red[((wave * 2 + 0) * 4 + r) * 64 + lane] = acc0[r];
      red[((wave * 2 + 1) * 4 + r) * 64 + lane] = acc1[r];
    }
    __syncthreads();

    for (int p = tid; p < 512; p += NTHR) {
      int b = p >> 4, rs = p & 15;
      int mt = b >> 4, quad = (b >> 2) & 3, reg = b & 3;
      int l2 = quad * 16 + rs;
      float s = biasp[rs];
#pragma unroll
      for (int w = 0; w < 4; ++w) s += red[((w * 2 + mt) * 4 + reg) * 64 + l2];
      gbuf[p] = s;
    }
    __syncthreads();

    // ---- pointwise LSTM cell (threads 0..127) ----
    if (tid < 128) {
      float gi = gbuf[pb * 16 + 0 + pc];
      float gf = gbuf[pb * 16 + 4 + pc];
      float gg = gbuf[pb * 16 + 8 + pc];
      float go = gbuf[pb * 16 + 12 + pc];
      float ig = 1.f / (1.f + __expf(-gi));
      float fg = 1.f / (1.f + __expf(-gf));
      float g2 = 1.f - 2.f / (1.f + __expf(2.f * gg));  // tanh
      float og = 1.f / (1.f + __expf(-go));
      creg = fg * creg + ig * g2;
      float hv = og * (1.f - 2.f / (1.f + __expf(2.f * creg)));

      out[((size_t)pb * Tn + t) * Hn + col] = hv;

      int nxt = cur ^ 1;
      int mt = pb >> 4;
      int kc2 = col >> 5;
      int l2 = (pb & 15) + (((col >> 3) & 3) << 4);
      int j = col & 7;
      hp[(((size_t)(nxt * 2 + mt) * 32 + kc2) * 64 + l2) * 8 + j] = (_Float16)hv;

      if (t == Tn - 1) {
        out[(size_t)Bn * Tn * Hn + (size_t)pb * Hn + col] = hv;                      // h_T
        out[(size_t)Bn * Tn * Hn + (size_t)Bn * Hn + (size_t)pb * Hn + col] = creg;  // c_T
      }
    }

    // ---- prefetch x for t+1 (h-independent; latency hides under barrier) ----
    {
      int tt = (t + 1 < Tn) ? t + 1 : t;
      const _Float16* xnb = xp + (size_t)tt * 2 * 16 * 64 * 8;
#pragma unroll
      for (int mt = 0; mt < 2; ++mt)
#pragma unroll
        for (int kk = 0; kk < 4; ++kk)
          xb[mt][kk] = *(const half8*)(xnb + ((size_t)(mt * 16 + wave * 4 + kk) * 64 + lane) * 8);
    }

    // drain all block stores (compiler emits vmcnt(0) before s_barrier)
    __syncthreads();

    // ---- flag-array grid barrier: 1 release store/block, wave 0 polls ----
    if (wave == 0) {
      if (lane == 0) {
        __threadfence();  // release: writeback L2 so h is visible cross-XCD
        __hip_atomic_store(flags + nb, t + 1, __ATOMIC_RELEASE, __HIP_MEMORY_SCOPE_AGENT);
      }
      const int tgt = t + 1;
      for (;;) {
        int a = __hip_atomic_load(flags + lane,       __ATOMIC_RELAXED, __HIP_MEMORY_SCOPE_AGENT);
        int b = __hip_atomic_load(flags + lane + 64,  __ATOMIC_RELAXED, __HIP_MEMORY_SCOPE_AGENT);
        int c = __hip_atomic_load(flags + lane + 128, __ATOMIC_RELAXED, __HIP_MEMORY_SCOPE_AGENT);
        int d = __hip_atomic_load(flags + lane + 192, __ATOMIC_RELAXED, __HIP_MEMORY_SCOPE_AGENT);
        int ok = (a >= tgt) & (b >= tgt) & (c >= tgt) & (d >= tgt);
        if (__all(ok)) break;
        __builtin_amdgcn_s_sleep(1);
      }
    }
    __syncthreads();
    __threadfence();  // acquire: invalidate stale L1/L2 before reading new h

    // rotate x prefetch buffer (register moves)
#pragma unroll
    for (int mt = 0; mt < 2; ++mt)
#pragma unroll
      for (int kk = 0; kk < 4; ++kk) xa[mt][kk] = xb[mt][kk];
  }
}

extern "C" void kernel_launch(void* const* d_in, const int* in_sizes, int n_in,
                              void* d_out, int out_size, void* d_ws, size_t ws_size,
                              hipStream_t stream) {
  const float* x   = (const float*)d_in[0];
  const float* Wih = (const float*)d_in[1];
  const float* Whh = (const float*)d_in[2];
  const float* bih = (const float*)d_in[3];
  const float* bhh = (const float*)d_in[4];
  float* out = (float*)d_out;

  char* ws = (char*)d_ws;
  _Float16* Wp   = (_Float16*)ws;                                  // 6,291,456 halves
  float*    bias = (float*)(ws + (size_t)6291456 * 2);             // 4096 floats
  _Float16* xp   = (_Float16*)(ws + (size_t)6291456 * 2 + 16384);  // 16,777,216 halves
  _Float16* hp   = xp + (size_t)16777216;                          // 65,536 halves
  int*      flags = (int*)(hp + 65536);

  prep_w_k<<<NBLK, NTHR, 0, stream>>>(Wih, Whh, bih, bhh, Wp, bias);
  prep_x_k<<<Tn, NTHR, 0, stream>>>(x, xp);
  hipMemsetAsync(hp, 0, 32768 * sizeof(_Float16), stream);  // zero h buffer 0
  hipMemsetAsync(flags, 0, NBLK * sizeof(int), stream);     // zero barrier flags
  lstm_k<<<NBLK, NTHR, 0, stream>>>(xp, Wp, bias, hp, flags, out);
}

// Round 3
// 18791.560 us; speedup vs baseline: 2.7745x; 1.5945x over previous
//
#include <hip/hip_runtime.h>
#include <stdint.h>
#include <stddef.h>

// Problem constants
#define Bn 32
#define Tn 1024
#define In 512
#define Hn 1024
#define NBLK 32    // persistent blocks; block owns 32 h-cols (128 gate rows)
#define NTHR 1024  // 16 waves = 8 ntiles x 2 mtiles, full K per wave
#define GP 132     // gbuf pitch (pad to break 128-float bank alias)

typedef _Float16 half8 __attribute__((ext_vector_type(8)));
typedef float float4x __attribute__((ext_vector_type(4)));
#define MFMA(a, b, c) __builtin_amdgcn_mfma_f32_16x16x32_f16((a), (b), (c), 0, 0, 0)

// ---------------------------------------------------------------------------
// Workspace:
//   Wp    : 32 nb * 8 nt * 48 kc * 512 = 6,291,456 halves (12.58 MB)
//   bias  : 4096 floats, [nb*128 + nt*16 + rsel]
//   xp    : 1024 t * 2 mt * 16 kc * 512 = 16,777,216 halves (33.55 MB)
//   hp    : 2 buf * 2 mt * 32 kc * 512 = 65,536 halves (128 KB), A-frag layout
//   flags : 32 * 16 ints (one per block, 64B-padded)
// NO fences anywhere: all cross-block data moves via agent-scope atomics
// (sc0 sc1 -> bypass non-coherent L1/L2), so no L2 wb/inv is ever required.
// ---------------------------------------------------------------------------

// Pack W = [W_ih | W_hh] into MFMA B-fragment-linear layout, fp16.
// Block nb owns h-cols [nb*32, nb*32+32). ntile nt: gate=nt>>1, half=nt&1;
// gate-row = gate*1024 + nb*32 + half*16 + (lane&15); k = kc*32+(lane>>4)*8+j.
__global__ void prep_w_k(const float* __restrict__ Wih, const float* __restrict__ Whh,
                         const float* __restrict__ bih, const float* __restrict__ bhh,
                         _Float16* __restrict__ Wp, float* __restrict__ bias) {
  int nb = blockIdx.x;
  for (int p = threadIdx.x; p < 8 * 48 * 64; p += blockDim.x) {
    int nt = p / (48 * 64);
    int rem = p % (48 * 64);
    int kc = rem >> 6, lane = rem & 63;
    int row = ((nt >> 1) << 10) + (nb << 5) + ((nt & 1) << 4) + (lane & 15);
    int kb = (kc << 5) + ((lane >> 4) << 3);
    half8 v;
#pragma unroll
    for (int j = 0; j < 8; ++j) {
      int k = kb + j;
      float w = (k < In) ? Wih[(size_t)row * In + k] : Whh[(size_t)row * Hn + (k - In)];
      v[j] = (_Float16)w;
    }
    *(half8*)(Wp + (((size_t)nb * 8 + nt) * 48 + kc) * 512 + lane * 8) = v;
  }
  if (threadIdx.x < 128) {
    int nt = threadIdx.x >> 4, r = threadIdx.x & 15;
    int row = ((nt >> 1) << 10) + (nb << 5) + ((nt & 1) << 4) + r;
    bias[nb * 128 + threadIdx.x] = bih[row] + bhh[row];
  }
}

// Convert inputs [B,T,I] fp32 -> A-fragment-linear fp16 per timestep.
// A row m = batch = (lane&15) + 16*mt ; k = kc*32 + (lane>>4)*8 + j.
__global__ void prep_x_k(const float* __restrict__ x, _Float16* __restrict__ xp) {
  int t = blockIdx.x;
  for (int p = threadIdx.x; p < 2048; p += blockDim.x) {
    int mt = p >> 10, rem = p & 1023, kc = rem >> 6, lane = rem & 63;
    int b = (lane & 15) + (mt << 4);
    int k = (kc << 5) + ((lane >> 4) << 3);
    const float* src = x + ((size_t)b * Tn + t) * In + k;
    half8 v;
#pragma unroll
    for (int j = 0; j < 8; ++j) v[j] = (_Float16)src[j];
    *(half8*)(xp + ((size_t)(t * 2 + mt) * 16 + kc) * 512 + lane * 8) = v;
  }
}

__global__ __launch_bounds__(NTHR, 4) void lstm_k(
    const _Float16* __restrict__ xp, const _Float16* __restrict__ Wp,
    const float* __restrict__ bias, _Float16* __restrict__ hp,
    int* __restrict__ flags, float* __restrict__ out) {
  // h staging buffer, identical linear layout to one hp buffer: [mt*32+kc]*512+lane*8+j
  __shared__ __attribute__((aligned(16))) _Float16 hs[2 * 32 * 512];  // 64 KB
  __shared__ float gbuf[32 * GP];                                     // 16.9 KB

  const int tid = threadIdx.x;
  const int wave = tid >> 6, lane = tid & 63;
  const int nb = blockIdx.x;
  const int nt = wave >> 1, mt = wave & 1;
  const int gate = nt >> 1, half_ = nt & 1;

  // ---- W resident in VGPRs for the whole sequence ----
  half8 wf[48];
  const _Float16* wb = Wp + ((size_t)nb * 8 + nt) * 48 * 512;
#pragma unroll
  for (int i = 0; i < 48; ++i) wf[i] = *(const half8*)(wb + (size_t)i * 512 + lane * 8);
  const float bv = bias[nb * 128 + nt * 16 + (lane & 15)];

  // pointwise identity (threads 0..511): batch pb, col pair 2*pc2, 2*pc2+1
  const int pb = tid >> 4, pc2 = tid & 15;
  float cr0 = 0.f, cr1 = 0.f;  // cell state in registers for whole sequence

  for (int t = 0; t < Tn; ++t) {
    const int cur = t & 1;

    // x fragments (plain loads; L2-cached — nothing invalidates L2 anymore)
    half8 xa[16];
    const _Float16* xbp = xp + ((size_t)t * 2 + mt) * 16 * 512;
#pragma unroll
    for (int kc = 0; kc < 16; ++kc)
      xa[kc] = *(const half8*)(xbp + (size_t)kc * 512 + lane * 8);

    // ---- stage h: 64 KB straight copy hp[cur] -> LDS, bypassing L1/L2 ----
    {
      const unsigned long long* hsrc =
          (const unsigned long long*)(hp + (size_t)cur * 32768);
      unsigned long long* hdst = (unsigned long long*)hs;
#pragma unroll
      for (int i = 0; i < 8; ++i) {
        int idx = tid + i * 1024;
        hdst[idx] = __hip_atomic_load(hsrc + idx, __ATOMIC_RELAXED, __HIP_MEMORY_SCOPE_AGENT);
      }
    }
    __syncthreads();

    // ---- full-K MFMA: 16 x-chunks + 32 h-chunks, 2 independent chains ----
    float4x a0 = {0.f, 0.f, 0.f, 0.f}, a1 = {0.f, 0.f, 0.f, 0.f};
#pragma unroll
    for (int kc = 0; kc < 16; kc += 2) {
      a0 = MFMA(xa[kc], wf[kc], a0);
      a1 = MFMA(xa[kc + 1], wf[kc + 1], a1);
    }
#pragma unroll
    for (int kc = 0; kc < 32; kc += 2) {
      half8 h0 = *(const half8*)(hs + (size_t)(mt * 32 + kc) * 512 + lane * 8);
      half8 h1 = *(const half8*)(hs + (size_t)(mt * 32 + kc + 1) * 512 + lane * 8);
      a0 = MFMA(h0, wf[16 + kc], a0);
      a1 = MFMA(h1, wf[17 + kc], a1);
    }

    // ---- gates to LDS: D layout col=lane&15 (rsel), row=(lane>>4)*4+r (b) ----
    {
      int brow = mt * 16 + (lane >> 4) * 4;
      int gcol = gate * 32 + half_ * 16 + (lane & 15);
#pragma unroll
      for (int r = 0; r < 4; ++r)
        gbuf[(brow + r) * GP + gcol] = a0[r] + a1[r] + bv;
    }
    __syncthreads();

    // ---- pointwise LSTM cell (threads 0..511, 2 cols each) ----
    if (tid < 512) {
      const int col = pc2 * 2;
      const float* gr = gbuf + pb * GP;
      float gi0 = gr[col],      gi1 = gr[col + 1];
      float gf0 = gr[32 + col], gf1 = gr[33 + col];
      float gg0 = gr[64 + col], gg1 = gr[65 + col];
      float go0 = gr[96 + col], go1 = gr[97 + col];

      float i0 = 1.f / (1.f + __expf(-gi0)), i1 = 1.f / (1.f + __expf(-gi1));
      float f0 = 1.f / (1.f + __expf(-gf0)), f1 = 1.f / (1.f + __expf(-gf1));
      float g0 = 1.f - 2.f / (1.f + __expf(2.f * gg0));
      float g1 = 1.f - 2.f / (1.f + __expf(2.f * gg1));
      float o0 = 1.f / (1.f + __expf(-go0)), o1 = 1.f / (1.f + __expf(-go1));
      cr0 = f0 * cr0 + i0 * g0;
      cr1 = f1 * cr1 + i1 * g1;
      float hv0 = o0 * (1.f - 2.f / (1.f + __expf(2.f * cr0)));
      float hv1 = o1 * (1.f - 2.f / (1.f + __expf(2.f * cr1)));

      size_t ob = ((size_t)pb * Tn + t) * Hn + nb * 32 + col;
      out[ob] = hv0;
      out[ob + 1] = hv1;

      // h -> hp[next] in A-frag layout, write-through (agent atomic, 2 halves)
      union { _Float16 h[2]; unsigned int u; } pk;
      pk.h[0] = (_Float16)hv0;
      pk.h[1] = (_Float16)hv1;
      int mtp = pb >> 4;
      int lanep = (pb & 15) + (((col >> 3) & 3) << 4);
      size_t hoff = ((size_t)((cur ^ 1) * 2 + mtp) * 32 + nb) * 512 + lanep * 8 + (col & 7);
      __hip_atomic_store((unsigned int*)(hp + hoff), pk.u,
                         __ATOMIC_RELAXED, __HIP_MEMORY_SCOPE_AGENT);

      if (t == Tn - 1) {
        size_t base = (size_t)Bn * Tn * Hn;
        out[base + (size_t)pb * Hn + nb * 32 + col] = hv0;      // h_T
        out[base + (size_t)pb * Hn + nb * 32 + col + 1] = hv1;
        out[base + (size_t)Bn * Hn + (size_t)pb * Hn + nb * 32 + col] = cr0;  // c_T
        out[base + (size_t)Bn * Hn + (size_t)pb * Hn + nb * 32 + col + 1] = cr1;
      }
    }

    // drain: compiler emits s_waitcnt vmcnt(0) before s_barrier, so every
    // wave's write-through h stores are at the coherence point after this.
    __syncthreads();

    // ---- contention-free grid barrier: 1 store/block, wave 0 polls ----
    if (wave == 0) {
      if (lane == 0)
        __hip_atomic_store(flags + nb * 16, t + 1, __ATOMIC_RELAXED, __HIP_MEMORY_SCOPE_AGENT);
      const int tgt = t + 1;
      for (;;) {
        int v = tgt;
        if (lane < NBLK)
          v = __hip_atomic_load(flags + lane * 16, __ATOMIC_RELAXED, __HIP_MEMORY_SCOPE_AGENT);
        if (__all(v >= tgt)) break;
        __builtin_amdgcn_s_sleep(1);
      }
    }
    __syncthreads();
  }
}

extern "C" void kernel_launch(void* const* d_in, const int* in_sizes, int n_in,
                              void* d_out, int out_size, void* d_ws, size_t ws_size,
                              hipStream_t stream) {
  const float* x   = (const float*)d_in[0];
  const float* Wih = (const float*)d_in[1];
  const float* Whh = (const float*)d_in[2];
  const float* bih = (const float*)d_in[3];
  const float* bhh = (const float*)d_in[4];
  float* out = (float*)d_out;

  char* ws = (char*)d_ws;
  _Float16* Wp   = (_Float16*)ws;                                  // 6,291,456 halves
  float*    bias = (float*)(ws + (size_t)6291456 * 2);             // 4096 floats
  _Float16* xp   = (_Float16*)(ws + (size_t)6291456 * 2 + 16384);  // 16,777,216 halves
  _Float16* hp   = xp + (size_t)16777216;                          // 65,536 halves
  int*      flags = (int*)(hp + 65536);                            // 32*16 ints

  prep_w_k<<<NBLK, 256, 0, stream>>>(Wih, Whh, bih, bhh, Wp, bias);
  prep_x_k<<<Tn, 256, 0, stream>>>(x, xp);
  hipMemsetAsync(hp, 0, 32768 * sizeof(_Float16), stream);   // zero h buffer 0
  hipMemsetAsync(flags, 0, NBLK * 16 * sizeof(int), stream); // zero barrier flags
  lstm_k<<<NBLK, NTHR, 0, stream>>>(xp, Wp, bias, hp, flags, out);
}